// Round 6
// baseline (480.989 us; speedup 1.0000x reference)
//
#include <hip/hip_runtime.h>
#include <hip/hip_bf16.h>
#include <stdint.h>

// Problem constants (fixed by the reference).
#define B_SZ 16384
#define K_SZ 5
#define H_SZ 512
#define E_SZ 512

typedef _Float16 f16;
typedef _Float16 f16x8 __attribute__((ext_vector_type(8)));
typedef float    f32x4 __attribute__((ext_vector_type(4)));

// ---------------------------------------------------------------------------
// async global->LDS, 16B per lane (gfx950). LDS dest must be wave-uniform
// base + lane*16.
__device__ __forceinline__ void gload_lds16(const void* g, void* l) {
  __builtin_amdgcn_global_load_lds(
      (const __attribute__((address_space(1))) unsigned int*)g,
      (__attribute__((address_space(3))) unsigned int*)l, 16, 0, 0);
}

__device__ __forceinline__ float fast_tanh(float x) {
  float e = __expf(-2.f * fabsf(x));      // in (0,1], no overflow
  float r = (1.f - e) / (1.f + e);
  return copysignf(r, x);
}

// ---------------------------------------------------------------------------
// prep_all: Wa->f16 (Wbig block 0), Ua->f16, Wa^T->f16, query->f16, zero bar.
// Grid = 4608 blocks of 256.
__global__ __launch_bounds__(256)
void prep_all(const float* __restrict__ Wa, const float* __restrict__ Ua,
              const float* __restrict__ query, f16* __restrict__ Wbig0,
              f16* __restrict__ Ua_h, f16* __restrict__ WaT,
              f16* __restrict__ q0h, unsigned* __restrict__ bar) {
  const int t = threadIdx.x;
  const int bb = blockIdx.x;
  if (bb == 0 && t == 0) *bar = 0u;
  if (bb < 128) {                      // cvt Wa -> Wbig block 0
    size_t o = ((size_t)bb * 256 + t) * 8;
    float4 a = *(const float4*)(Wa + o);
    float4 b = *(const float4*)(Wa + o + 4);
    union { f16 h[8]; uint4 u; } u;
    u.h[0] = (f16)a.x; u.h[1] = (f16)a.y; u.h[2] = (f16)a.z; u.h[3] = (f16)a.w;
    u.h[4] = (f16)b.x; u.h[5] = (f16)b.y; u.h[6] = (f16)b.z; u.h[7] = (f16)b.w;
    *(uint4*)(Wbig0 + o) = u.u;
  } else if (bb < 256) {               // cvt Ua -> Ua_h
    size_t o = ((size_t)(bb - 128) * 256 + t) * 8;
    float4 a = *(const float4*)(Ua + o);
    float4 b = *(const float4*)(Ua + o + 4);
    union { f16 h[8]; uint4 u; } u;
    u.h[0] = (f16)a.x; u.h[1] = (f16)a.y; u.h[2] = (f16)a.z; u.h[3] = (f16)a.w;
    u.h[4] = (f16)b.x; u.h[5] = (f16)b.y; u.h[6] = (f16)b.z; u.h[7] = (f16)b.w;
    *(uint4*)(Ua_h + o) = u.u;
  } else if (bb < 512) {               // transpose Wa -> WaT (f16)
    __shared__ float tile[32][33];
    int blk = bb - 256;                // 256 blocks = 16x16 tiles of 32x32
    int bx = blk & 15, by = blk >> 4;
    int tx = t & 31, ty = t >> 5;      // 32x8
    #pragma unroll
    for (int i = 0; i < 32; i += 8)
      tile[ty + i][tx] = Wa[(size_t)(by * 32 + ty + i) * 512 + bx * 32 + tx];
    __syncthreads();
    #pragma unroll
    for (int i = 0; i < 32; i += 8)
      WaT[(size_t)(bx * 32 + ty + i) * 512 + by * 32 + tx] =
          (f16)tile[tx][ty + i];
  } else {                             // cvt query -> q0h (4096 blocks)
    size_t o = ((size_t)(bb - 512) * 256 + t) * 8;
    float4 a = *(const float4*)(query + o);
    float4 b = *(const float4*)(query + o + 4);
    union { f16 h[8]; uint4 u; } u;
    u.h[0] = (f16)a.x; u.h[1] = (f16)a.y; u.h[2] = (f16)a.z; u.h[3] = (f16)a.w;
    u.h[4] = (f16)b.x; u.h[5] = (f16)b.y; u.h[6] = (f16)b.z; u.h[7] = (f16)b.w;
    *(uint4*)(q0h + o) = u.u;
  }
}

// ---------------------------------------------------------------------------
// Device-scope barrier for the 16-block power_chain kernel. Monotonic counter
// (zeroed by prep_all), release/acquire via fences + agent-scope atomics.
__device__ __forceinline__ void gbar(unsigned* cnt, unsigned target) {
  __syncthreads();
  if (threadIdx.x == 0) {
    __threadfence();                   // release: tile writes visible device-wide
    __hip_atomic_fetch_add(cnt, 1u, __ATOMIC_ACQ_REL, __HIP_MEMORY_SCOPE_AGENT);
    while (__hip_atomic_load(cnt, __ATOMIC_ACQUIRE,
                             __HIP_MEMORY_SCOPE_AGENT) < target)
      __builtin_amdgcn_s_sleep(2);
    __threadfence();                   // acquire: don't read stale tiles
  }
  __syncthreads();
}

// All 4 dependent Wa-power GEMMs in one launch. Grid = 16 blocks (co-resident
// by construction), 128x128 tile each, global barrier between steps.
__global__ __launch_bounds__(256)
void power_chain(const f16* __restrict__ WaT, f16* __restrict__ Wbig,
                 unsigned* __restrict__ bar) {
  __shared__ f16 As[128 * 32];
  __shared__ f16 Bs[128 * 32];
  const int t = threadIdx.x, l = t & 63, wid = t >> 6;
  const int wm = wid >> 1, wn = wid & 1;
  const int mt = blockIdx.x >> 2, nt = blockIdx.x & 3;
  const int m0 = mt * 128, n0 = nt * 128;
  const int lrow = l & 15, lk = (l >> 4) * 8;

  for (int j = 1; j < K_SZ; ++j) {
    const f16* A = Wbig + (size_t)(j - 1) * (512 * 512);
    f16* Y = Wbig + (size_t)j * (512 * 512);
    f32x4 acc[4][4] = {};
    for (int k0 = 0; k0 < 512; k0 += 32) {
      #pragma unroll
      for (int p = 0; p < 2; ++p) {
        int c = p * 256 + t, row = c >> 2, seg = c & 3;
        gload_lds16(WaT + (size_t)(n0 + row) * 512 + k0 + seg * 8,
                    (char*)Bs + c * 16);
        gload_lds16(A + (size_t)(m0 + row) * 512 + k0 + seg * 8,
                    (char*)As + c * 16);
      }
      __syncthreads();
      f16x8 af[4], bf[4];
      #pragma unroll
      for (int mi = 0; mi < 4; ++mi)
        af[mi] = *(const f16x8*)(As + (wm * 64 + mi * 16 + lrow) * 32 + lk);
      #pragma unroll
      for (int ni = 0; ni < 4; ++ni)
        bf[ni] = *(const f16x8*)(Bs + (wn * 64 + ni * 16 + lrow) * 32 + lk);
      #pragma unroll
      for (int mi = 0; mi < 4; ++mi)
        #pragma unroll
        for (int ni = 0; ni < 4; ++ni)
          acc[mi][ni] = __builtin_amdgcn_mfma_f32_16x16x32_f16(
              af[mi], bf[ni], acc[mi][ni], 0, 0, 0);
      __syncthreads();
    }
    #pragma unroll
    for (int mi = 0; mi < 4; ++mi)
      #pragma unroll
      for (int j2 = 0; j2 < 4; ++j2) {
        size_t row = m0 + wm * 64 + mi * 16 + ((l >> 4) << 2) + j2;
        #pragma unroll
        for (int ni = 0; ni < 4; ++ni)
          Y[row * 512 + n0 + wn * 64 + ni * 16 + lrow] = (f16)acc[mi][ni][j2];
      }
    if (j < K_SZ - 1) gbar(bar, 16u * (unsigned)j);
  }
}

// ---------------------------------------------------------------------------
// Fused: X[b,k,h] = sum_e topics[b,k,e]*Ua[h,e] + sum_c q0[b,c]*Wa^k[h,c],
// epilogue: partials[nt*2+wn][k][b] = sum over this block's 128 h of
// va[h]*tanh(X). 2-phase double-buffered pipeline: stage(t+1) BEFORE
// compute(t), one barrier per K-step (T3-min + T14 load-early/write-late).
__global__ __launch_bounds__(256)
void fused_score_gemm(const float* __restrict__ topics,
                      const f16* __restrict__ q0h,
                      const f16* __restrict__ Ua_h,
                      const f16* __restrict__ Wbig,
                      const float* __restrict__ va_w,
                      float* __restrict__ partials) {
  __shared__ f16 As[2][128 * 32];
  __shared__ f16 Bs[2][128 * 32];
  const int t = threadIdx.x;
  const int l = t & 63, wid = t >> 6;
  const int wm = wid >> 1, wn = wid & 1;
  int bid = blockIdx.x;
  const int nwg = gridDim.x;               // 2560, %8==0
  bid = (bid & 7) * (nwg >> 3) + (bid >> 3);
  const int kq = bid >> 9;                 // 512 blocks per k-slice
  const int rem = bid & 511;
  const int mt = rem >> 2, nt = rem & 3;   // consecutive bids share mt -> L2
  const size_t m0 = (size_t)mt * 128;
  const int n0 = nt * 128;
  const int lrow = l & 15;
  const int lk = (l >> 4) * 8;
  const f16* Pk = Wbig + (size_t)kq * (512 * 512);

  // per-thread staging bases
  // phase-1 A (fp32 topics, reg-staged): chunk c=p*256+t -> row=p*32+(t>>3),
  // seg=t&7; lds byte = row*64 + seg*8
  const float* tA = topics + ((m0 + (t >> 3)) * K_SZ + kq) * (size_t)E_SZ +
                    (t & 7) * 4;
  const int ldsA1 = (t >> 3) * 64 + (t & 7) * 8;
  // 16B-chunk staging (B tiles, and phase-2 A): c=p*256+t -> row=p*64+(t>>2),
  // seg=t&3; lds byte = c*16
  const f16* tB1 = Ua_h + (size_t)(n0 + (t >> 2)) * 512 + (t & 3) * 8;
  const f16* tB2 = Pk + (size_t)(n0 + (t >> 2)) * 512 + (t & 3) * 8;
  const f16* tA2 = q0h + (m0 + (t >> 2)) * (size_t)H_SZ + (t & 3) * 8;

  float4 areg[4];
  f32x4 acc[4][4] = {};

  auto stage1 = [&](int k0, int buf) {
    #pragma unroll
    for (int p = 0; p < 2; ++p)
      gload_lds16(tB1 + (size_t)p * 64 * 512 + k0,
                  (char*)Bs[buf] + (p * 256 + t) * 16);
    #pragma unroll
    for (int p = 0; p < 4; ++p)
      areg[p] = *(const float4*)(tA + (size_t)p * 32 * K_SZ * E_SZ + k0);
  };
  auto write1 = [&](int buf) {
    #pragma unroll
    for (int p = 0; p < 4; ++p) {
      union { f16 h[4]; uint2 u; } cv;
      cv.h[0] = (f16)areg[p].x; cv.h[1] = (f16)areg[p].y;
      cv.h[2] = (f16)areg[p].z; cv.h[3] = (f16)areg[p].w;
      *(uint2*)((char*)As[buf] + p * 2048 + ldsA1) = cv.u;
    }
  };
  auto stage2 = [&](int k0, int buf) {
    #pragma unroll
    for (int p = 0; p < 2; ++p) {
      gload_lds16(tB2 + (size_t)p * 64 * 512 + k0,
                  (char*)Bs[buf] + (p * 256 + t) * 16);
      gload_lds16(tA2 + (size_t)p * 64 * H_SZ + k0,
                  (char*)As[buf] + (p * 256 + t) * 16);
    }
  };
  auto compute = [&](int buf) {
    f16x8 af[4], bf[4];
    #pragma unroll
    for (int mi = 0; mi < 4; ++mi)
      af[mi] = *(const f16x8*)(As[buf] + (wm * 64 + mi * 16 + lrow) * 32 + lk);
    #pragma unroll
    for (int ni = 0; ni < 4; ++ni)
      bf[ni] = *(const f16x8*)(Bs[buf] + (wn * 64 + ni * 16 + lrow) * 32 + lk);
    #pragma unroll
    for (int mi = 0; mi < 4; ++mi)
      #pragma unroll
      for (int ni = 0; ni < 4; ++ni)
        acc[mi][ni] = __builtin_amdgcn_mfma_f32_16x16x32_f16(
            af[mi], bf[ni], acc[mi][ni], 0, 0, 0);
  };

  // prologue: tile 0 into buf 0
  stage1(0, 0);
  write1(0);                 // compiler inserts vmcnt wait on areg
  __syncthreads();           // drains gload_lds + ds_write

  // phase 1: topics x Ua, iters 0..15
  #pragma unroll 2
  for (int i = 0; i < 16; ++i) {
    const int cur = i & 1;
    if (i < 15) stage1((i + 1) * 32, cur ^ 1);
    else        stage2(0, cur ^ 1);          // first tile of phase 2
    compute(cur);
    if (i < 15) write1(cur ^ 1);
    __syncthreads();
  }
  // phase 2: q0 x Wa^k, iters 0..15 (buffer parity continues: i&1)
  #pragma unroll 2
  for (int i = 0; i < 16; ++i) {
    const int cur = i & 1;
    if (i < 15) stage2((i + 1) * 32, cur ^ 1);
    compute(cur);
    __syncthreads();
  }

  // epilogue: partial score = sum_h va[h]*tanh(X) over this block's 128 cols.
  const int colbase = n0 + wn * 64 + lrow;
  float va4[4];
  #pragma unroll
  for (int ni = 0; ni < 4; ++ni) va4[ni] = va_w[colbase + ni * 16];

  #pragma unroll
  for (int mi = 0; mi < 4; ++mi) {
    #pragma unroll
    for (int j = 0; j < 4; ++j) {
      float s = 0.f;
      #pragma unroll
      for (int ni = 0; ni < 4; ++ni)
        s += va4[ni] * fast_tanh(acc[mi][ni][j]);
      #pragma unroll
      for (int m = 1; m < 16; m <<= 1) s += __shfl_xor(s, m);
      if (lrow == 0) {
        int row = (int)m0 + wm * 64 + mi * 16 + ((l >> 4) << 2) + j;
        partials[(size_t)(nt * 2 + wn) * (K_SZ * B_SZ) + kq * B_SZ + row] = s;
      }
    }
  }
}

// ---------------------------------------------------------------------------
// scores (from 8 partial slices) -> softmax -> mt. One wave per b row.
__global__ __launch_bounds__(256)
void finalize2(const float* __restrict__ partials,
               const float* __restrict__ topics, const float* __restrict__ cov,
               const float* __restrict__ va_b, float* __restrict__ out) {
  const int wid = threadIdx.x >> 6, l = threadIdx.x & 63;
  const size_t b = (size_t)blockIdx.x * 4 + wid;
  const float vb = va_b[0];

  float s[K_SZ];
  #pragma unroll
  for (int k = 0; k < K_SZ; ++k) {
    float raw = 0.f;
    #pragma unroll
    for (int sl = 0; sl < 8; ++sl)
      raw += partials[(size_t)sl * (K_SZ * B_SZ) + k * B_SZ + b];
    s[k] = (raw + vb) * cov[b * K_SZ + k];
  }

  float m = s[0];
  #pragma unroll
  for (int k = 1; k < K_SZ; ++k) m = fmaxf(m, s[k]);
  float a[K_SZ], d = 0.f;
  #pragma unroll
  for (int k = 0; k < K_SZ; ++k) { a[k] = __expf(s[k] - m); d += a[k]; }
  float inv = 1.f / d;
  #pragma unroll
  for (int k = 0; k < K_SZ; ++k) a[k] *= inv;

  float acc0[4] = {}, acc1[4] = {};
  #pragma unroll
  for (int k = 0; k < K_SZ; ++k) {
    const float* tp = topics + (b * K_SZ + k) * E_SZ + l * 8;
    float4 t0 = *(const float4*)tp;
    float4 t1 = *(const float4*)(tp + 4);
    acc0[0] += a[k] * t0.x; acc0[1] += a[k] * t0.y;
    acc0[2] += a[k] * t0.z; acc0[3] += a[k] * t0.w;
    acc1[0] += a[k] * t1.x; acc1[1] += a[k] * t1.y;
    acc1[2] += a[k] * t1.z; acc1[3] += a[k] * t1.w;
  }
  float* mo = out + b * E_SZ + l * 8;
  *(float4*)mo       = make_float4(acc0[0], acc0[1], acc0[2], acc0[3]);
  *(float4*)(mo + 4) = make_float4(acc1[0], acc1[1], acc1[2], acc1[3]);
  if (l < K_SZ) {
    float av = (l == 0) ? a[0] : (l == 1) ? a[1] : (l == 2) ? a[2]
               : (l == 3) ? a[3] : a[4];
    out[(size_t)B_SZ * E_SZ + b * K_SZ + l] = av;
  }
}

// ---------------------------------------------------------------------------
extern "C" void kernel_launch(void* const* d_in, const int* in_sizes, int n_in,
                              void* d_out, int out_size, void* d_ws, size_t ws_size,
                              hipStream_t stream) {
  const float* query  = (const float*)d_in[0];
  const float* topics = (const float*)d_in[1];
  const float* cov    = (const float*)d_in[2];
  const float* Ua     = (const float*)d_in[3];
  const float* Wa     = (const float*)d_in[4];
  const float* va_w   = (const float*)d_in[5];
  const float* va_b   = (const float*)d_in[6];
  float* out = (float*)d_out;

  char* ws = (char*)d_ws;
  size_t off = 0;
  auto alloc = [&](size_t bytes) -> char* {
    char* p = ws + off;
    off += (bytes + 255) & ~(size_t)255;
    return p;
  };
  f16* q0h   = (f16*)alloc((size_t)B_SZ * H_SZ * 2);             // 16.8 MB
  f16* Ua_h  = (f16*)alloc((size_t)H_SZ * E_SZ * 2);             // 0.5 MB
  f16* WaT   = (f16*)alloc((size_t)H_SZ * H_SZ * 2);             // 0.5 MB
  f16* Wbig  = (f16*)alloc((size_t)K_SZ * H_SZ * H_SZ * 2);      // 2.6 MB
  float* partials = (float*)alloc((size_t)8 * K_SZ * B_SZ * 4);  // 2.6 MB
  unsigned* bar   = (unsigned*)alloc(256);

  prep_all<<<4608, 256, 0, stream>>>(Wa, Ua, query, Wbig, Ua_h, WaT, q0h, bar);
  power_chain<<<16, 256, 0, stream>>>(WaT, Wbig, bar);
  fused_score_gemm<<<K_SZ * (B_SZ / 128) * (H_SZ / 128), 256, 0, stream>>>(
      topics, q0h, Ua_h, Wbig, va_w, partials);
  finalize2<<<B_SZ / 4, 256, 0, stream>>>(partials, topics, cov, va_b, out);
}